// Round 6
// baseline (811.168 us; speedup 1.0000x reference)
//
#include <hip/hip_runtime.h>

// EGNN fused layer, MI355X gfx950. Round 6.
// R5 post-mortem: work (VALU/MFMA busy-time) identical to R3; stalls doubled.
// Real wall = 53.6M global atomic lane-ops (~64-128/cyc device-wide => 175-350us).
// R6: counting-sort edges into 16-node dst buckets (prep); per-bucket LDS f32
// accumulation (ds_add_f32) + exclusive-owner non-atomic flush. ZERO global
// atomics. dst-side gathers become bucket-local (L1-hot). Main loop structure
// reverted to proven R3 (single mlds buffer, full __syncthreads).

#define NN 50000
#define NE 800000
#define NDIM 64
#define HDIM 128
#define NBUCK 3125            // dst>>4 buckets, 16 nodes each (exact: 3125*16=50000)
#define MSTRIDE 168           // m_input LDS row stride (ushort): 160 + 8 pad
#define HSTRIDE 136           // hidden LDS row stride (ushort): 128 + 8 pad
#define NH (NN * NDIM)
#define NX (NN * 3)

// ws layout (bytes), total ~16.1 MB
#define WS_HBF    0           // ushort[NN*64]      6,400,000
#define WS_SRCS   6400000     // int[NE]            3,200,000  (bucket-sorted src)
#define WS_DSTS   9600000     // int[NE]            3,200,000  (bucket-sorted dst)
#define WS_DISTS  12800000    // float[NE]          3,200,000  (bucket-sorted dist)
#define WS_WN1P   16000000    // ushort[160*128]       40,960
#define WS_WC1P   16040960    // ushort[160*128]       40,960
#define WS_BN1P   16081920    // float[128]               512
#define WS_BC1P   16082432    // float[128]               512
#define WS_START  16082944    // int[NBUCK+1]          12,504
#define WS_CURS   16095448    // int[NBUCK+1]          12,504  (hist during prep)

typedef __bf16 bf16x8 __attribute__((ext_vector_type(8)));
typedef float f32x4 __attribute__((ext_vector_type(4)));
typedef unsigned short ushort8 __attribute__((ext_vector_type(8)));
typedef unsigned short ushort4v __attribute__((ext_vector_type(4)));

__device__ __forceinline__ unsigned short f2bf(float f) {
    union { float f; unsigned int u; } c; c.f = f;
    unsigned int r = c.u + 0x7fffu + ((c.u >> 16) & 1u);   // RNE
    return (unsigned short)(r >> 16);
}
__device__ __forceinline__ unsigned int pk2bf(float a, float b) {
    return (unsigned int)f2bf(a) | ((unsigned int)f2bf(b) << 16);
}
__device__ __forceinline__ float silu(float v) {
    return v * __builtin_amdgcn_rcpf(1.0f + __expf(-v));
}
__device__ __forceinline__ bf16x8 ld_frag(const unsigned short* p) {
    union { ushort8 u; bf16x8 v; } c;
    c.u = *(const ushort8*)p;
    return c.v;
}
__device__ __forceinline__ bf16x8 mk_frag(const unsigned short* u) {
    union { ushort8 uu; bf16x8 v; } c;
#pragma unroll
    for (int j = 0; j < 8; ++j) c.uu[j] = u[j];
    return c.v;
}

// Fused prep: out init + hbf (837500 float4), fused weights (20480), zero hist (3126)
__global__ void prep_all(
    const float* __restrict__ h, const float* __restrict__ x,
    const float* __restrict__ We2, const float* __restrict__ be2,
    const float* __restrict__ Wn1, const float* __restrict__ bn1,
    const float* __restrict__ Wc1, const float* __restrict__ bc1,
    float* __restrict__ out, unsigned short* __restrict__ hbf,
    unsigned short* __restrict__ wn1p, unsigned short* __restrict__ wc1p,
    float* __restrict__ bn1p, float* __restrict__ bc1p, int* __restrict__ hist) {
    int gid = blockIdx.x * 256 + threadIdx.x;
    if (gid < 837500) {
        if (gid < 800000) {
            float4 v = ((const float4*)h)[gid];
            ((float4*)out)[gid] = v;
            ushort4v u = { f2bf(v.x), f2bf(v.y), f2bf(v.z), f2bf(v.w) };
            ((ushort4v*)hbf)[gid] = u;
        } else {
            ((float4*)out)[gid] = ((const float4*)x)[gid - 800000];
        }
    } else if (gid < 837500 + 20480) {
        int idx = gid - 837500;
        int k = idx >> 7, n = idx & 127;
        float vn, vc;
        if (k < 128) {
            vn = Wn1[k * HDIM + n];
            vc = Wc1[k * HDIM + n];
        } else {
            int i = k - 128;
            float sn = 0.0f, sc = 0.0f;
            for (int j = 0; j < 32; ++j) {
                float wv = We2[i * 32 + j];
                sn += wv * Wn1[(128 + j) * HDIM + n];
                sc += wv * Wc1[(128 + j) * HDIM + n];
            }
            vn = sn; vc = sc;
        }
        wn1p[idx] = f2bf(vn);
        wc1p[idx] = f2bf(vc);
        if (idx < 128) {
            float sn = bn1[idx], sc = bc1[idx];
            for (int j = 0; j < 32; ++j) {
                sn += be2[j] * Wn1[(128 + j) * HDIM + idx];
                sc += be2[j] * Wc1[(128 + j) * HDIM + idx];
            }
            bn1p[idx] = sn;
            bc1p[idx] = sc;
        }
    } else if (gid < 837500 + 20480 + NBUCK + 1) {
        hist[gid - (837500 + 20480)] = 0;
    }
}

__global__ void prep_hist(const int* __restrict__ dstg, int* __restrict__ hist) {
    int e = blockIdx.x * 256 + threadIdx.x;
    if (e < NE) atomicAdd(&hist[dstg[e] >> 4], 1);
}

// exclusive scan of curs (=hist) into start AND curs. Single block, 256 threads.
__global__ void prep_scan(int* curs, int* start) {
    __shared__ int sd[256];
    __shared__ int carry_s;
    const int tid = threadIdx.x;
    if (tid == 0) carry_s = 0;
    __syncthreads();
    for (int c = 0; c < 13; ++c) {           // 13*256 = 3328 >= NBUCK+1
        const int i = c * 256 + tid;
        const int v = (i < NBUCK) ? curs[i] : 0;
        sd[tid] = v;
        __syncthreads();
        for (int off = 1; off < 256; off <<= 1) {
            int t = (tid >= off) ? sd[tid - off] : 0;
            __syncthreads();
            sd[tid] += t;
            __syncthreads();
        }
        const int excl = sd[tid] - v + carry_s;
        if (i <= NBUCK) { start[i] = excl; curs[i] = excl; }
        __syncthreads();
        if (tid == 0) carry_s += sd[255];
        __syncthreads();
    }
}

__global__ void prep_scatter(const int* __restrict__ srcg, const int* __restrict__ dstg,
                             const float* __restrict__ dist, int* __restrict__ curs,
                             int* __restrict__ src_s, int* __restrict__ dst_s,
                             float* __restrict__ dist_s) {
    int e = blockIdx.x * 256 + threadIdx.x;
    if (e < NE) {
        int d = dstg[e];
        int pos = atomicAdd(&curs[d >> 4], 1);
        src_s[pos] = srcg[e];
        dst_s[pos] = d;
        dist_s[pos] = dist[e];
    }
}

__global__ __launch_bounds__(256, 2) void egnn_edges(
    const unsigned short* __restrict__ hbf, const float* __restrict__ x,
    const int* __restrict__ src_s, const int* __restrict__ dst_s,
    const float* __restrict__ dist_s, const int* __restrict__ start,
    const float* __restrict__ We1, const float* __restrict__ be1,
    const unsigned short* __restrict__ wn1p, const float* __restrict__ bn1p,
    const float* __restrict__ Wn2, const float* __restrict__ bn2,
    const unsigned short* __restrict__ wc1p, const float* __restrict__ bc1p,
    const float* __restrict__ Wc2,
    float* __restrict__ outh, float* __restrict__ outx) {

    __shared__ __align__(16) unsigned short mlds[64 * MSTRIDE];  // 21.5 KB
    __shared__ __align__(16) unsigned short hl[64 * HSTRIDE];    // 17.4 KB
    __shared__ __align__(16) float nodeacc[16][68];              // 4.3 KB (+pad)
    __shared__ float xacc[16][3];
    __shared__ int src_l[64];
    __shared__ int dst_l[64];
    __shared__ float dist_l[64];
    __shared__ float part_l[256];

    const int tid  = threadIdx.x;
    const int w    = tid >> 6;
    const int lane = tid & 63;
    const int l15  = lane & 15;
    const int quad = lane >> 4;
    // butterfly output: this lane ends with coord partial for this edge
    const int bedge = ((l15 >> 2) << 4) + (quad << 2) + (l15 & 3);

    // ---- one-time: B-fragments to registers ----
    bf16x8 wn1f[5][2], wc1f[5][2];
#pragma unroll
    for (int kc = 0; kc < 5; ++kc) {
#pragma unroll
        for (int nt = 0; nt < 2; ++nt) {
            unsigned short un_[8], uc_[8];
            const int n = w * 32 + l15 * 2 + nt;
#pragma unroll
            for (int j = 0; j < 8; ++j) {
                const int k = kc * 32 + quad * 8 + j;
                un_[j] = wn1p[k * HDIM + n];
                uc_[j] = wc1p[k * HDIM + n];
            }
            wn1f[kc][nt] = mk_frag(un_);
            wc1f[kc][nt] = mk_frag(uc_);
        }
    }
    bf16x8 wn2f[4];
#pragma unroll
    for (int kc = 0; kc < 4; ++kc) {
        unsigned short u[8];
        const int n = w * 16 + l15;
#pragma unroll
        for (int j = 0; j < 8; ++j) {
            const int k = kc * 32 + quad * 8 + j;
            u[j] = f2bf(Wn2[k * NDIM + n]);
        }
        wn2f[kc] = mk_frag(u);
    }
    float we1r[8], be1r[8];
#pragma unroll
    for (int j = 0; j < 8; ++j) {
        we1r[j] = We1[w * 8 + j];
        be1r[j] = be1[w * 8 + j];
    }
    const float biasN0 = bn1p[w * 32 + l15 * 2];
    const float biasN1 = bn1p[w * 32 + l15 * 2 + 1];
    const float biasC0 = bc1p[w * 32 + l15 * 2];
    const float biasC1 = bc1p[w * 32 + l15 * 2 + 1];
    const float bias2v = bn2[w * 16 + l15];
    const float wc2a = Wc2[w * 32 + l15 * 2];
    const float wc2b = Wc2[w * 32 + l15 * 2 + 1];

    for (int b = blockIdx.x; b < NBUCK; b += gridDim.x) {
        const int base_node = b << 4;
        const int e_start = start[b];
        const int e_end = start[b + 1];

        // zero bucket accumulators (first tile's barrier orders vs use)
        for (int i = tid; i < 16 * 68; i += 256) ((float*)nodeacc)[i] = 0.0f;
        if (tid < 48) ((float*)xacc)[tid] = 0.0f;

        for (int e0 = e_start; e0 < e_end; e0 += 64) {
            const int cnt = min(64, e_end - e0);
            __syncthreads();   // zeroing done / prev epilogue reads of *_l done

            if (tid < 64) {
                const int ee = e0 + ((tid < cnt) ? tid : (cnt - 1));  // clamp tail
                src_l[tid] = src_s[ee];
                dst_l[tid] = dst_s[ee];
                dist_l[tid] = dist_s[ee];
            }
            __syncthreads();

            // ---- stage m_input = [h_src | h_dst | s] bf16 ----
            {
                const int c8 = tid & 7, sub = tid >> 3;
#pragma unroll
                for (int it = 0; it < 2; ++it) {
                    const int el = sub + it * 32;
                    const ushort8 hs = *(const ushort8*)(hbf + src_l[el] * NDIM + c8 * 8);
                    const ushort8 hd = *(const ushort8*)(hbf + dst_l[el] * NDIM + c8 * 8);
                    *(ushort8*)&mlds[el * MSTRIDE + c8 * 8] = hs;
                    *(ushort8*)&mlds[el * MSTRIDE + 64 + c8 * 8] = hd;
                }
            }
            {
                const float dv = dist_l[lane];
                ushort8 su;
#pragma unroll
                for (int j = 0; j < 8; ++j)
                    su[j] = f2bf(silu(fmaf(dv, we1r[j], be1r[j])));
                *(ushort8*)&mlds[lane * MSTRIDE + 128 + w * 8] = su;
            }
            __syncthreads();

            // ---- GEMM1: [64x160] @ {Wn1', Wc1'} ----
            f32x4 accN[4][2], accC[4][2];
#pragma unroll
            for (int mt = 0; mt < 4; ++mt) {
                accN[mt][0] = (f32x4){biasN0, biasN0, biasN0, biasN0};
                accN[mt][1] = (f32x4){biasN1, biasN1, biasN1, biasN1};
                accC[mt][0] = (f32x4){biasC0, biasC0, biasC0, biasC0};
                accC[mt][1] = (f32x4){biasC1, biasC1, biasC1, biasC1};
            }
#pragma unroll
            for (int kc = 0; kc < 5; ++kc) {
                bf16x8 af[4];
#pragma unroll
                for (int mt = 0; mt < 4; ++mt)
                    af[mt] = ld_frag(&mlds[(mt * 16 + l15) * MSTRIDE + kc * 32 + quad * 8]);
#pragma unroll
                for (int mt = 0; mt < 4; ++mt) {
#pragma unroll
                    for (int nt = 0; nt < 2; ++nt) {
                        accN[mt][nt] = __builtin_amdgcn_mfma_f32_16x16x32_bf16(
                            af[mt], wn1f[kc][nt], accN[mt][nt], 0, 0, 0);
                        accC[mt][nt] = __builtin_amdgcn_mfma_f32_16x16x32_bf16(
                            af[mt], wc1f[kc][nt], accC[mt][nt], 0, 0, 0);
                    }
                }
            }

            // ---- node path: silu -> paired b32 writes (A-layout) ----
#pragma unroll
            for (int mt = 0; mt < 4; ++mt) {
#pragma unroll
                for (int r = 0; r < 4; ++r) {
                    const int row = mt * 16 + quad * 4 + r;
                    *(unsigned int*)&hl[row * HSTRIDE + w * 32 + l15 * 2] =
                        pk2bf(silu(accN[mt][0][r]), silu(accN[mt][1][r]));
                }
            }
            __syncthreads();

            // ---- GEMM2 node -> LDS accumulation (ds_add_f32, no global atomics) ----
            f32x4 acc2[4];
#pragma unroll
            for (int mt = 0; mt < 4; ++mt) acc2[mt] = (f32x4){bias2v, bias2v, bias2v, bias2v};
#pragma unroll
            for (int kc = 0; kc < 4; ++kc) {
#pragma unroll
                for (int mt = 0; mt < 4; ++mt) {
                    bf16x8 a2 = ld_frag(&hl[(mt * 16 + l15) * HSTRIDE + kc * 32 + quad * 8]);
                    acc2[mt] = __builtin_amdgcn_mfma_f32_16x16x32_bf16(a2, wn2f[kc], acc2[mt], 0, 0, 0);
                }
            }
#pragma unroll
            for (int mt = 0; mt < 4; ++mt) {
#pragma unroll
                for (int r = 0; r < 4; ++r) {
                    const int el = mt * 16 + quad * 4 + r;
                    if (el < cnt)
                        atomicAdd(&nodeacc[dst_l[el] - base_node][w * 16 + l15], acc2[mt][r]);
                }
            }

            // ---- coord path: silu*Wc2 + shfl_xor fold -> part_l ----
            {
                float vals[16];
#pragma unroll
                for (int mt = 0; mt < 4; ++mt)
#pragma unroll
                    for (int r = 0; r < 4; ++r)
                        vals[mt * 4 + r] = silu(accC[mt][0][r]) * wc2a +
                                           silu(accC[mt][1][r]) * wc2b;
#pragma unroll
                for (int m = 8; m >= 1; m >>= 1) {
                    const bool up = (l15 & m) != 0;
#pragma unroll
                    for (int j = 0; j < 8; ++j) {
                        if (j < m) {
                            float send = up ? vals[j] : vals[j + m];
                            float recv = __shfl_xor(send, m, 64);
                            vals[j] = (up ? vals[j + m] : vals[j]) + recv;
                        }
                    }
                }
                part_l[w * 64 + bedge] = vals[0];
            }
            __syncthreads();

            if (tid < cnt) {
                const float cw = part_l[tid] + part_l[64 + tid] + part_l[128 + tid] + part_l[192 + tid];
                const int sn = src_l[tid], dn = dst_l[tid];
                const float dx = x[sn * 3 + 0] - x[dn * 3 + 0];
                const float dy = x[sn * 3 + 1] - x[dn * 3 + 1];
                const float dz = x[sn * 3 + 2] - x[dn * 3 + 2];
                float len = sqrtf(dx * dx + dy * dy + dz * dz);
                len = fmaxf(len, 1e-8f);
                const float f = cw / len;
                const int rel = dn - base_node;
                atomicAdd(&xacc[rel][0], f * dx);
                atomicAdd(&xacc[rel][1], f * dy);
                atomicAdd(&xacc[rel][2], f * dz);
            }
        }
        __syncthreads();   // all tiles' LDS adds done

        // ---- exclusive-owner flush: out[bucket nodes] += acc (non-atomic) ----
        {
            const int node = tid >> 4;
            const int c4 = (tid & 15) * 4;
            const float4 add = *(const float4*)&nodeacc[node][c4];
            float* op = outh + (base_node + node) * NDIM + c4;
            float4 cur = *(const float4*)op;
            cur.x += add.x; cur.y += add.y; cur.z += add.z; cur.w += add.w;
            *(float4*)op = cur;
        }
        if (tid < 48) {
            const int node = tid / 3, c = tid - node * 3;
            outx[(base_node + node) * 3 + c] += xacc[node][c];
        }
        __syncthreads();   // flush reads done before next bucket zeroes LDS
    }
}

extern "C" void kernel_launch(void* const* d_in, const int* in_sizes, int n_in,
                              void* d_out, int out_size, void* d_ws, size_t ws_size,
                              hipStream_t stream) {
    const float* h    = (const float*)d_in[0];
    const float* x    = (const float*)d_in[1];
    const int*   ei   = (const int*)d_in[2];
    const float* dist = (const float*)d_in[3];
    const float* We1  = (const float*)d_in[4];
    const float* be1  = (const float*)d_in[5];
    const float* We2  = (const float*)d_in[6];
    const float* be2  = (const float*)d_in[7];
    const float* Wn1  = (const float*)d_in[8];
    const float* bn1  = (const float*)d_in[9];
    const float* Wn2  = (const float*)d_in[10];
    const float* bn2  = (const float*)d_in[11];
    const float* Wc1  = (const float*)d_in[12];
    const float* bc1  = (const float*)d_in[13];
    const float* Wc2  = (const float*)d_in[14];

    unsigned short* hbf   = (unsigned short*)((char*)d_ws + WS_HBF);
    int*            src_s = (int*)((char*)d_ws + WS_SRCS);
    int*            dst_s = (int*)((char*)d_ws + WS_DSTS);
    float*          dist_s= (float*)((char*)d_ws + WS_DISTS);
    unsigned short* wn1p  = (unsigned short*)((char*)d_ws + WS_WN1P);
    unsigned short* wc1p  = (unsigned short*)((char*)d_ws + WS_WC1P);
    float* bn1p  = (float*)((char*)d_ws + WS_BN1P);
    float* bc1p  = (float*)((char*)d_ws + WS_BC1P);
    int*   startb= (int*)((char*)d_ws + WS_START);
    int*   curs  = (int*)((char*)d_ws + WS_CURS);

    float* outh = (float*)d_out;
    float* outx = outh + (size_t)NH;

    const int prep_items = 837500 + 20480 + NBUCK + 1;
    prep_all<<<(prep_items + 255) / 256, 256, 0, stream>>>(
        h, x, We2, be2, Wn1, bn1, Wc1, bc1,
        (float*)d_out, hbf, wn1p, wc1p, bn1p, bc1p, curs);
    prep_hist<<<(NE + 255) / 256, 256, 0, stream>>>(ei + NE, curs);
    prep_scan<<<1, 256, 0, stream>>>(curs, startb);
    prep_scatter<<<(NE + 255) / 256, 256, 0, stream>>>(ei, ei + NE, dist, curs,
                                                       src_s, dst_s, dist_s);
    egnn_edges<<<512, 256, 0, stream>>>(hbf, x, src_s, dst_s, dist_s, startb,
                                        We1, be1, wn1p, bn1p,
                                        Wn2, bn2, wc1p, bc1p, Wc2,
                                        outh, outx);
}